// Round 7
// baseline (6301.009 us; speedup 1.0000x reference)
//
#include <hip/hip_runtime.h>
#include <hip/hip_bf16.h>

// SARDecoder round 7: persistent step kernel. Key change vs r6: NO acquire
// fences (no buffer_inv L2 nukes). Cross-block state via device-scope relaxed
// atomics (L2-bypass, L3-coherent); weights/fpj/feat stay L2-cached.
// B=32, RNN=ATT=FEAT=512, V1=111, H=8, W=32, STEPS=31, P=256.

#define RNN   512
#define V1    111
#define STEPS 31
#define HWP   256
#define NBM   128
#define NATT  32
#define XS_F  9216   // 256 x 36 half-K stage
#define POOLF 9760

typedef unsigned short ushortT;
typedef unsigned int   uintT;

__device__ __forceinline__ float blo(uintT u){ union { uintT i; float f; } v; v.i = u << 16; return v.f; }
__device__ __forceinline__ float bhi(uintT u){ union { uintT i; float f; } v; v.i = u & 0xffff0000u; return v.f; }
__device__ __forceinline__ ushortT f2b(float f){
  __hip_bfloat16 h = __float2bfloat16(f);
  union { __hip_bfloat16 b; ushortT s; } v; v.b = h; return v.s;
}
__device__ __forceinline__ uintT packbf(float lo, float hi){
  return (uintT)f2b(lo) | ((uintT)f2b(hi) << 16);
}
__device__ __forceinline__ float sigf(float x){ return 1.f/(1.f + __expf(-x)); }
__device__ __forceinline__ float tanh_f(float x){ float e = __expf(2.f*x); return 1.f - 2.f/(e+1.f); }

// device-scope uncached (L3-coherent) access — no cache-invalidate needed
__device__ __forceinline__ float ld_uc(const float* p){
  return __hip_atomic_load(p, __ATOMIC_RELAXED, __HIP_MEMORY_SCOPE_AGENT);
}
__device__ __forceinline__ void st_uc(float* p, float v){
  __hip_atomic_store(p, v, __ATOMIC_RELAXED, __HIP_MEMORY_SCOPE_AGENT);
}

// ---------------- init: zero st + sps + bar ----------------
__global__ __launch_bounds__(256) void k_init(float* __restrict__ p){
  p[blockIdx.x*256 + threadIdx.x] = 0.f;   // grid 1282*256 = 328192 exact
}

// ---------------- conv-weight transpose: Wf[a][c][i] -> wtc[cp][i][a] bf16-pair ----------------
__global__ __launch_bounds__(256) void k_tconv(const float* __restrict__ Wf,
                                               uintT* __restrict__ wtc){
  int o = blockIdx.x*256 + threadIdx.x;       // 1,179,648
  int a  = o / 2304;
  int r  = o - a*2304;
  int cp = r / 9;
  int i  = r - cp*9;
  float v0 = Wf[(size_t)a*4608 + (size_t)(2*cp)*9 + i];
  float v1 = Wf[(size_t)a*4608 + (size_t)(2*cp)*9 + 9 + i];
  wtc[((size_t)cp*9 + i)*512 + a] = packbf(v0, v1);
}

// ---------------- elementwise bf16 packers ----------------
__global__ __launch_bounds__(256) void k_wgate(const float* __restrict__ w0,
    const float* __restrict__ w1, const float* __restrict__ w2, uintT* __restrict__ o){
  int idx = blockIdx.x*256 + threadIdx.x;    // 1,572,864
  int m = idx >> 19, r = idx & 524287;
  const float* s = (m==0)? w0 : (m==1)? w1 : w2;
  float2 v = *(const float2*)(s + 2*(size_t)r);
  o[idx] = packbf(v.x, v.y);
}
__global__ __launch_bounds__(256) void k_woutb(const float* __restrict__ W, uintT* __restrict__ o){
  int idx = blockIdx.x*256 + threadIdx.x;    // 56,832
  float2 v = *(const float2*)(W + 2*(size_t)idx);
  o[idx] = packbf(v.x, v.y);
}
__global__ __launch_bounds__(256) void k_featb(const float* __restrict__ F, uintT* __restrict__ o){
  int idx = blockIdx.x*256 + threadIdx.x;    // 2,097,152
  float2 v = *(const float2*)(F + 2*(size_t)idx);
  o[idx] = packbf(v.x, v.y);
}

// ---------------- M0[j][g] = sum_k wih0[j][k] * Wemb[k][g] ----------------
__global__ __launch_bounds__(128) void k_m0(const float* __restrict__ wih0,
                                            const float* __restrict__ Wemb,
                                            float* __restrict__ M0){
  int j = blockIdx.x, g = threadIdx.x;
  if (g < V1){
    float acc = 0.f;
    const float* wr = wih0 + (size_t)j*512;
    for (int k=0;k<512;k++) acc += wr[k] * Wemb[(size_t)k*V1 + g];
    M0[(size_t)j*112 + g] = acc;
  }
}

// ---------------- conv 3x3 SAME -> fpj bf16 (b,p,a); grid b32 x y8 x ah2 x xh4 ----------------
__global__ __launch_bounds__(256) void k_conv(const float* __restrict__ feat,
                                              const uintT* __restrict__ wtc,
                                              const float* __restrict__ bfv,
                                              ushortT* __restrict__ fpj){
  int bid = blockIdx.x;
  int b  = bid >> 6;
  int y  = (bid >> 3) & 7;
  int ah = (bid >> 2) & 1;
  int xh = bid & 3;
  int a  = ah*256 + threadIdx.x;
  int x0 = xh*8;
  float acc[8];
  float bias = bfv[a];
  #pragma unroll
  for (int x=0;x<8;x++) acc[x]=bias;
  for (int cp=0; cp<256; cp++){
    uintT wq[9];
    #pragma unroll
    for (int i=0;i<9;i++) wq[i] = wtc[((size_t)cp*9 + i)*512 + a];   // coalesced
    #pragma unroll
    for (int cc=0; cc<2; cc++){
      float w[9];
      #pragma unroll
      for (int i=0;i<9;i++) w[i] = cc ? bhi(wq[i]) : blo(wq[i]);
      #pragma unroll
      for (int ky=0; ky<3; ky++){
        int yy = y + ky - 1;
        if (yy < 0 || yy > 7) continue;       // uniform per block
        const float* fr = feat + (((size_t)b*512 + cp*2+cc)*8 + yy)*32 + x0;
        float in[10];
        in[0] = (x0 == 0)  ? 0.f : fr[-1];
        #pragma unroll
        for (int i=0;i<8;i++) in[i+1] = fr[i];
        in[9] = (x0 == 24) ? 0.f : fr[8];
        float w0=w[ky*3+0], w1=w[ky*3+1], w2=w[ky*3+2];
        #pragma unroll
        for (int x=0;x<8;x++)
          acc[x] += w0*in[x] + w1*in[x+1] + w2*in[x+2];
      }
    }
  }
  #pragma unroll
  for (int x=0;x<8;x++)
    fpj[((size_t)b*HWP + (size_t)(y*32 + x0 + x))*512 + a] = f2b(acc[x]);
}

// ---------------- hierarchical grid barrier: RELEASE arrivals, RELAXED polls ----------------
// No acquire fence: consumers read shared data with ld_uc (L3-coherent).
__device__ __forceinline__ void mbar(int* __restrict__ bar, int bid, int round, bool wait){
  __syncthreads();
  if (threadIdx.x == 0){
    int* leaf = bar + 16 + (bid >> 3)*16;
    int old = __hip_atomic_fetch_add(leaf, 1, __ATOMIC_RELEASE, __HIP_MEMORY_SCOPE_AGENT);
    if (old == round*8 + 7)
      __hip_atomic_fetch_add(bar, 1, __ATOMIC_RELEASE, __HIP_MEMORY_SCOPE_AGENT);
    if (wait){
      int target = 16*(round+1);
      while (__hip_atomic_load(bar, __ATOMIC_RELAXED, __HIP_MEMORY_SCOPE_AGENT) < target)
        __builtin_amdgcn_s_sleep(1);
    }
  }
  __syncthreads();
}

// ---------------- stage half-K (256 k x 32 b) of [512][32] state into xs[k][36] ----------------
__device__ __forceinline__ void stage_half(float* __restrict__ xs,
                                           const float* __restrict__ srcT,
                                           int half, int tid){
  const float* s = srcT + half*8192;
  #pragma unroll
  for (int i=0;i<16;i++){
    int idx = tid + i*512;
    xs[(idx >> 5)*36 + (idx & 31)] = ld_uc(s + idx);
  }
}

// ---------------- bf16-weight GEMM quarter ----------------
__device__ __forceinline__ void gemm_half_b(float acc[4][4], const uintT* __restrict__ wb,
                                            const float* __restrict__ xs,
                                            int koff, int kq, int jq, int bq, int u0){
  const uintT* w0 = wb + ((size_t)(jq*512 + u0))*256 + ((koff + kq*16) >> 1);
  const float* xp = xs + (kq*16)*36 + bq*4;
  #pragma unroll
  for (int kk=0; kk<16; kk+=8){
    float xv[8][4];
    #pragma unroll
    for (int i=0;i<8;i++){
      float4 tv = *(const float4*)(xp + (kk+i)*36);
      xv[i][0]=tv.x; xv[i][1]=tv.y; xv[i][2]=tv.z; xv[i][3]=tv.w;
    }
    #pragma unroll
    for (int r=0;r<4;r++){
      uint4 wq = *(const uint4*)(w0 + (size_t)r*256 + (kk>>1));
      float wf[8] = {blo(wq.x),bhi(wq.x),blo(wq.y),bhi(wq.y),
                     blo(wq.z),bhi(wq.z),blo(wq.w),bhi(wq.w)};
      #pragma unroll
      for (int bb=0;bb<4;bb++){
        float s = 0.f;
        #pragma unroll
        for (int i=0;i<8;i++) s += wf[i]*xv[i][bb];
        acc[r][bb] += s;
      }
    }
  }
}

// ---------------- persistent 31-step kernel: 128 GEMM blocks + 32 att blocks ----------------
__global__ __launch_bounds__(512) void k_steps(
    const int* __restrict__ gt, const float* __restrict__ M0,
    const uintT* __restrict__ wgb,
    const float* __restrict__ bih0, const float* __restrict__ bhh0,
    const float* __restrict__ bih1, const float* __restrict__ bhh1,
    const ushortT* __restrict__ featb, const ushortT* __restrict__ fpj,
    const float* __restrict__ Wst, const float* __restrict__ watt,
    const uintT* __restrict__ Woutb, const float* __restrict__ bout,
    float* __restrict__ st, float* __restrict__ spsr,
    int* __restrict__ bar, float* __restrict__ out)
{
  __shared__ __align__(16) float pool[POOLF];
  const int tid = threadIdx.x, bid = blockIdx.x;
  float* h0T0   = st;
  float* h0T1   = st + 16384;
  float* h1ring = st + 32768;           // 8 slots x [512][32]
  float* c0T    = st + 163840;          // block-private -> plain cached
  float* c1T    = st + 180224;
  int* attdone = bar + 300;             // single aggregated att-step counter

  if (bid < NBM){
    // ================= main GEMM block: 4 units (u0..u0+3) =================
    float* xs   = pool;
    float* part = pool;                 // overlay after GEMM
    float* gsum = pool + XS_F;
    const int kq = tid >> 5, jq = (tid >> 3) & 3, bq = tid & 7;
    const int al = tid >> 5;            // used when tid<128 (0..3)
    const int bsp = tid & 31;
    const int u0 = bid*4;
    const uintT* whh0b = wgb;
    const uintT* wih1b = wgb + 524288;
    const uintT* whh1b = wgb + 1048576;

    for (int t=0; t<STEPS; t++){
      const float* h0r = (t & 1) ? h0T0 : h0T1;
      float*       h0w = (t & 1) ? h0T1 : h0T0;
      const float* h1r = h1ring + (size_t)((t+7)&7)*16384;
      float*       h1w = h1ring + (size_t)(t&7)*16384;

      // ---------- phase 1: gates0 = M0[:,g] + h0_prev @ whh0^T ; cell0 ----------
      float acc[4][4] = {{0.f}};
      stage_half(xs, h0r, 0, tid); __syncthreads();
      gemm_half_b(acc, whh0b, xs, 0,   kq, jq, bq, u0); __syncthreads();
      stage_half(xs, h0r, 1, tid); __syncthreads();
      gemm_half_b(acc, whh0b, xs, 256, kq, jq, bq, u0); __syncthreads();
      #pragma unroll
      for (int r=0;r<4;r++)
        #pragma unroll
        for (int bb=0;bb<4;bb++)
          part[(kq*16 + jq*4 + r)*33 + bq*4 + bb] = acc[r][bb];
      __syncthreads();
      {
        int jj = tid >> 5, b = tid & 31;
        float s = 0.f;
        #pragma unroll
        for (int k2=0;k2<16;k2++) s += part[(k2*16 + jj)*33 + b];
        int m = jj >> 2, ul = jj & 3;
        int j = m*512 + u0 + ul;
        s += bih0[j] + bhh0[j];
        if (t > 0) s += M0[(size_t)j*112 + gt[b*STEPS + t - 1]];
        gsum[jj*33 + b] = s;
      }
      __syncthreads();
      if (tid < 128){
        int ul = tid >> 5, b = tid & 31;
        float gi = gsum[(0*4+ul)*33 + b], gf = gsum[(1*4+ul)*33 + b];
        float gg = gsum[(2*4+ul)*33 + b], go = gsum[(3*4+ul)*33 + b];
        int idx = (u0+ul)*32 + b;
        float cn = sigf(gf)*c0T[idx] + sigf(gi)*tanh_f(gg);
        c0T[idx] = cn;
        st_uc(&h0w[idx], sigf(go)*tanh_f(cn));
      }
      mbar(bar, bid, t, true);

      // ---------- phase 2: gates1 = h0 @ wih1^T + h1_prev @ whh1^T ; sp(t-1) ; cell1 ----------
      #pragma unroll
      for (int r=0;r<4;r++){ acc[r][0]=0.f; acc[r][1]=0.f; acc[r][2]=0.f; acc[r][3]=0.f; }
      float spacc = 0.f;
      stage_half(xs, h0w, 0, tid); __syncthreads();
      gemm_half_b(acc, wih1b, xs, 0,   kq, jq, bq, u0); __syncthreads();
      stage_half(xs, h0w, 1, tid); __syncthreads();
      gemm_half_b(acc, wih1b, xs, 256, kq, jq, bq, u0); __syncthreads();
      stage_half(xs, h1r, 0, tid); __syncthreads();
      gemm_half_b(acc, whh1b, xs, 0,   kq, jq, bq, u0);
      if (tid < 128){
        const float* wr = Wst + (size_t)(u0+al)*512;
        #pragma unroll 4
        for (int kl=0; kl<256; kl+=4){
          float4 wv = *(const float4*)(wr + kl);
          spacc += wv.x*xs[(kl+0)*36+bsp] + wv.y*xs[(kl+1)*36+bsp]
                 + wv.z*xs[(kl+2)*36+bsp] + wv.w*xs[(kl+3)*36+bsp];
        }
      }
      __syncthreads();
      stage_half(xs, h1r, 1, tid); __syncthreads();
      gemm_half_b(acc, whh1b, xs, 256, kq, jq, bq, u0);
      if (tid < 128){
        const float* wr = Wst + (size_t)(u0+al)*512 + 256;
        #pragma unroll 4
        for (int kl=0; kl<256; kl+=4){
          float4 wv = *(const float4*)(wr + kl);
          spacc += wv.x*xs[(kl+0)*36+bsp] + wv.y*xs[(kl+1)*36+bsp]
                 + wv.z*xs[(kl+2)*36+bsp] + wv.w*xs[(kl+3)*36+bsp];
        }
      }
      __syncthreads();
      #pragma unroll
      for (int r=0;r<4;r++)
        #pragma unroll
        for (int bb=0;bb<4;bb++)
          part[(kq*16 + jq*4 + r)*33 + bq*4 + bb] = acc[r][bb];
      __syncthreads();
      // back-pressure: ring slack 8, require att lag <= 5 (single counter)
      if (tid == 0 && t >= 6){
        int tgt = 32*(t - 5);
        while (__hip_atomic_load(attdone, __ATOMIC_RELAXED, __HIP_MEMORY_SCOPE_AGENT) < tgt)
          __builtin_amdgcn_s_sleep(2);
      }
      __syncthreads();
      {
        int jj = tid >> 5, b = tid & 31;
        float s = 0.f;
        #pragma unroll
        for (int k2=0;k2<16;k2++) s += part[(k2*16 + jj)*33 + b];
        int m = jj >> 2, ul = jj & 3;
        int j = m*512 + u0 + ul;
        s += bih1[j] + bhh1[j];
        gsum[jj*33 + b] = s;
      }
      __syncthreads();
      if (tid < 128){
        int ul = tid >> 5, b = tid & 31;
        float gi = gsum[(0*4+ul)*33 + b], gf = gsum[(1*4+ul)*33 + b];
        float gg = gsum[(2*4+ul)*33 + b], go = gsum[(3*4+ul)*33 + b];
        int idx = (u0+ul)*32 + b;
        float cn = sigf(gf)*c1T[idx] + sigf(gi)*tanh_f(gg);
        c1T[idx] = cn;
        st_uc(&h1w[idx], sigf(go)*tanh_f(cn));
        if (t >= 1)
          st_uc(&spsr[(size_t)((t+7)&7)*16384 + (size_t)b*512 + (u0+al)], spacc);
      }
    }
    // epilogue: sp(STEPS-1)
    mbar(bar, bid, STEPS, true);
    {
      const float* h1l = h1ring + (size_t)((STEPS-1)&7)*16384;
      float spacc = 0.f;
      stage_half(xs, h1l, 0, tid); __syncthreads();
      if (tid < 128){
        const float* wr = Wst + (size_t)(u0+al)*512;
        for (int kl=0; kl<256; kl+=4){
          float4 wv = *(const float4*)(wr + kl);
          spacc += wv.x*xs[(kl+0)*36+bsp] + wv.y*xs[(kl+1)*36+bsp]
                 + wv.z*xs[(kl+2)*36+bsp] + wv.w*xs[(kl+3)*36+bsp];
        }
      }
      __syncthreads();
      stage_half(xs, h1l, 1, tid); __syncthreads();
      if (tid < 128){
        const float* wr = Wst + (size_t)(u0+al)*512 + 256;
        for (int kl=0; kl<256; kl+=4){
          float4 wv = *(const float4*)(wr + kl);
          spacc += wv.x*xs[(kl+0)*36+bsp] + wv.y*xs[(kl+1)*36+bsp]
                 + wv.z*xs[(kl+2)*36+bsp] + wv.w*xs[(kl+3)*36+bsp];
        }
        st_uc(&spsr[(size_t)((STEPS-1)&7)*16384 + (size_t)bsp*512 + (u0+al)], spacc);
      }
    }
    mbar(bar, bid, STEPS+1, false);
  } else {
    // ================= attention block (one batch item) =================
    const int b = bid - NBM;
    float* h1s   = pool;
    float* spsl  = pool + 512;
    float* watts = pool + 1024;
    float* pals  = pool + 1536;
    float* attw  = pool + 2048;
    float* glim  = pool + 2304;
    float* red   = pool + 2816;
    watts[tid] = watt[tid];

    for (int t=0; t<STEPS; t++){
      if (tid == 0){
        int target = 16*(t+3);     // ph2(t+1) complete => h1(t) and sp(t) ready
        while (__hip_atomic_load(bar, __ATOMIC_RELAXED, __HIP_MEMORY_SCOPE_AGENT) < target)
          __builtin_amdgcn_s_sleep(4);
      }
      __syncthreads();
      h1s[tid]  = ld_uc(&h1ring[(size_t)(t&7)*16384 + tid*32 + b]);
      spsl[tid] = ld_uc(&spsr[(size_t)(t&7)*16384 + (size_t)b*512 + tid]);
      __syncthreads();
      // attention logits over (p, a-half)
      {
        int p = tid & 255, ac = tid >> 8;
        const uint4* fr = (const uint4*)(fpj + ((size_t)b*HWP + p)*512 + ac*256);
        float al2 = 0.f;
        #pragma unroll 8
        for (int kb=0;kb<32;kb++){
          uint4 q = fr[kb];
          float v[8] = {blo(q.x),bhi(q.x),blo(q.y),bhi(q.y),blo(q.z),bhi(q.z),blo(q.w),bhi(q.w)};
          int a0 = ac*256 + kb*8;
          #pragma unroll
          for (int i=0;i<8;i++)
            al2 += watts[a0+i] * tanh_f(v[i] + spsl[a0+i]);
        }
        pals[tid] = al2;
      }
      __syncthreads();
      // softmax over 256 positions
      {
        float al2 = (tid < 256) ? (pals[tid] + pals[256+tid]) : -1e30f;
        float m = al2;
        #pragma unroll
        for (int off=32; off>0; off>>=1) m = fmaxf(m, __shfl_xor(m, off));
        if (tid < 256 && (tid & 63)==0) red[tid>>6] = m;
        __syncthreads();
        m = fmaxf(fmaxf(red[0],red[1]), fmaxf(red[2],red[3]));
        float e = (tid < 256) ? __expf(al2 - m) : 0.f;
        float s = e;
        #pragma unroll
        for (int off=32; off>0; off>>=1) s += __shfl_xor(s, off);
        __syncthreads();
        if (tid < 256 && (tid & 63)==0) red[tid>>6] = s;
        __syncthreads();
        if (tid < 256){
          float sa = red[0]+red[1]+red[2]+red[3];
          attw[tid] = e / sa;
        }
      }
      __syncthreads();
      // glimpse[c] = sum_p featb[b,c,p] * attw[p]
      {
        const uint4* fr = (const uint4*)(featb + ((size_t)b*512 + tid)*HWP);
        float acc = 0.f;
        #pragma unroll 8
        for (int kb=0;kb<32;kb++){
          uint4 q = fr[kb];
          const float* aw = attw + kb*8;
          acc += blo(q.x)*aw[0] + bhi(q.x)*aw[1] + blo(q.y)*aw[2] + bhi(q.y)*aw[3]
               + blo(q.z)*aw[4] + bhi(q.z)*aw[5] + blo(q.w)*aw[6] + bhi(q.w)*aw[7];
        }
        glim[tid] = acc;
      }
      __syncthreads();
      // logits = [h1, glimpse] @ Wout^T + b_out  (bf16 weights)
      if (tid < V1){
        const uint4* wr = (const uint4*)(Woutb + (size_t)tid*512);
        float acc = bout[tid];
        #pragma unroll 8
        for (int kb=0;kb<64;kb++){
          uint4 q = wr[kb];
          const float* hx = h1s + kb*8;
          acc += blo(q.x)*hx[0] + bhi(q.x)*hx[1] + blo(q.y)*hx[2] + bhi(q.y)*hx[3]
               + blo(q.z)*hx[4] + bhi(q.z)*hx[5] + blo(q.w)*hx[6] + bhi(q.w)*hx[7];
        }
        #pragma unroll 8
        for (int kb=0;kb<64;kb++){
          uint4 q = wr[64+kb];
          const float* gx = glim + kb*8;
          acc += blo(q.x)*gx[0] + bhi(q.x)*gx[1] + blo(q.y)*gx[2] + bhi(q.y)*gx[3]
               + blo(q.z)*gx[4] + bhi(q.z)*gx[5] + blo(q.w)*gx[6] + bhi(q.w)*gx[7];
        }
        out[(size_t)b*STEPS*V1 + (size_t)t*V1 + tid] = acc;
      }
      __syncthreads();
      if (tid == 0)
        __hip_atomic_fetch_add(attdone, 1, __ATOMIC_RELEASE, __HIP_MEMORY_SCOPE_AGENT);
    }
  }
}

extern "C" void kernel_launch(void* const* d_in, const int* in_sizes, int n_in,
                              void* d_out, int out_size, void* d_ws, size_t ws_size,
                              hipStream_t stream)
{
  const float* features = (const float*)d_in[0];
  const int*   gt       = (const int*)d_in[2];
  const float* Wf    = (const float*)d_in[3];
  const float* bfv   = (const float*)d_in[4];
  const float* Wst   = (const float*)d_in[5];
  const float* watt  = (const float*)d_in[6];
  const float* Wemb  = (const float*)d_in[7];
  const float* wih0  = (const float*)d_in[8];
  const float* whh0  = (const float*)d_in[9];
  const float* bih0  = (const float*)d_in[10];
  const float* bhh0  = (const float*)d_in[11];
  const float* wih1  = (const float*)d_in[12];
  const float* whh1  = (const float*)d_in[13];
  const float* bih1  = (const float*)d_in[14];
  const float* bhh1  = (const float*)d_in[15];
  const float* Wout  = (const float*)d_in[16];
  const float* bout  = (const float*)d_in[17];
  float* out = (float*)d_out;

  // ---- workspace layout (bytes), total ~25.5 MB; wtc overlaid by featb ----
  char* wsb = (char*)d_ws;
  ushortT* fpj   = (ushortT*)(wsb + 0);          //  8,388,608 persist
  uintT*   wtc   = (uintT*)  (wsb + 8388608);    //  4,718,592 transient (conv only)
  ushortT* featb = (ushortT*)(wsb + 8388608);    //  8,388,608 persist (written after conv)
  float*   M0    = (float*)  (wsb + 16777216);   //    917,504
  uintT*   wgb   = (uintT*)  (wsb + 17694720);   //  6,291,456 (whh0|wih1|whh1 bf16)
  uintT*   Woutb = (uintT*)  (wsb + 23986176);   //    227,328
  float*   st    = (float*)  (wsb + 24213504);   //    786,432 (h0 x2, h1 ring x8, c0, c1)
  float*   spsr  = (float*)  (wsb + 24999936);   //    524,288 (sps ring x8)
  int*     bar   = (int*)    (wsb + 25524224);   //      2,048

  k_init <<<1282, 256, 0, stream>>>(st);                  // zeros st + sps + bar
  k_tconv<<<4608, 256, 0, stream>>>(Wf, wtc);
  k_conv <<<2048, 256, 0, stream>>>(features, wtc, bfv, fpj);
  k_featb<<<8192, 256, 0, stream>>>(features, (uintT*)featb);   // overwrites wtc region
  k_wgate<<<6144, 256, 0, stream>>>(whh0, wih1, whh1, wgb);
  k_woutb<<<222, 256, 0, stream>>>(Wout, Woutb);
  k_m0   <<<2048, 128, 0, stream>>>(wih0, Wemb, M0);
  k_steps<<<NBM + NATT, 512, 0, stream>>>(gt, M0, wgb, bih0, bhh0, bih1, bhh1,
                                          featb, fpj, Wst, watt, Woutb, bout,
                                          st, spsr, bar, out);
  (void)in_sizes; (void)n_in; (void)out_size; (void)ws_size;
}

// Round 8
// 2728.710 us; speedup vs baseline: 2.3092x; 2.3092x over previous
//
#include <hip/hip_runtime.h>
#include <hip/hip_bf16.h>

// SARDecoder round 8: software-pipelined multi-launch design. ZERO atomics /
// fences / polling — stream-ordered dispatch is the barrier (HW coherent,
// ~3us). Launch L: roleA = gates0+cell0(L), roleB = gates1+cell1(L-1),
// roleC = attention(L-2) incl. its own sp = WstT @ h1 (coalesced bf16).
// h0/h1 parity double-buffered. B=32, RNN=ATT=FEAT=512, V1=111, STEPS=31.

#define RNN   512
#define V1    111
#define STEPS 31
#define HWP   256
#define XS_F  9216   // 256 x 36 half-K stage
#define POOLF 9760

typedef unsigned short ushortT;
typedef unsigned int   uintT;

__device__ __forceinline__ float blo(uintT u){ union { uintT i; float f; } v; v.i = u << 16; return v.f; }
__device__ __forceinline__ float bhi(uintT u){ union { uintT i; float f; } v; v.i = u & 0xffff0000u; return v.f; }
__device__ __forceinline__ ushortT f2b(float f){
  __hip_bfloat16 h = __float2bfloat16(f);
  union { __hip_bfloat16 b; ushortT s; } v; v.b = h; return v.s;
}
__device__ __forceinline__ uintT packbf(float lo, float hi){
  return (uintT)f2b(lo) | ((uintT)f2b(hi) << 16);
}
__device__ __forceinline__ float sigf(float x){ return 1.f/(1.f + __expf(-x)); }
__device__ __forceinline__ float tanh_f(float x){ float e = __expf(2.f*x); return 1.f - 2.f/(e+1.f); }

// ---------------- init: zero states (98304 f32: h0 x2, h1 x2, c0, c1) ----------------
__global__ __launch_bounds__(256) void k_init(float* __restrict__ p){
  p[blockIdx.x*256 + threadIdx.x] = 0.f;   // grid 384
}

// ---------------- conv-weight transpose: Wf[a][c][i] -> wtc[cp][i][a] bf16-pair ----------------
__global__ __launch_bounds__(256) void k_tconv(const float* __restrict__ Wf,
                                               uintT* __restrict__ wtc){
  int o = blockIdx.x*256 + threadIdx.x;       // 1,179,648
  int a  = o / 2304;
  int r  = o - a*2304;
  int cp = r / 9;
  int i  = r - cp*9;
  float v0 = Wf[(size_t)a*4608 + (size_t)(2*cp)*9 + i];
  float v1 = Wf[(size_t)a*4608 + (size_t)(2*cp)*9 + 9 + i];
  wtc[((size_t)cp*9 + i)*512 + a] = packbf(v0, v1);
}

// ---------------- bf16 packers ----------------
__global__ __launch_bounds__(256) void k_wgate(const float* __restrict__ w0,
    const float* __restrict__ w1, const float* __restrict__ w2, uintT* __restrict__ o){
  int idx = blockIdx.x*256 + threadIdx.x;    // 1,572,864
  int m = idx >> 19, r = idx & 524287;
  const float* s = (m==0)? w0 : (m==1)? w1 : w2;
  float2 v = *(const float2*)(s + 2*(size_t)r);
  o[idx] = packbf(v.x, v.y);
}
__global__ __launch_bounds__(256) void k_woutb(const float* __restrict__ W, uintT* __restrict__ o){
  int idx = blockIdx.x*256 + threadIdx.x;    // 56,832
  float2 v = *(const float2*)(W + 2*(size_t)idx);
  o[idx] = packbf(v.x, v.y);
}
__global__ __launch_bounds__(256) void k_featb(const float* __restrict__ F, uintT* __restrict__ o){
  int idx = blockIdx.x*256 + threadIdx.x;    // 2,097,152
  float2 v = *(const float2*)(F + 2*(size_t)idx);
  o[idx] = packbf(v.x, v.y);
}
// WstT[u][ap] = pack(Wst[2ap][u], Wst[2ap+1][u])  (coalesced sp-GEMV layout)
__global__ __launch_bounds__(256) void k_wstT(const float* __restrict__ Wst, uintT* __restrict__ o){
  int idx = blockIdx.x*256 + threadIdx.x;    // 131,072
  int u = idx >> 8, ap = idx & 255;
  o[idx] = packbf(Wst[(size_t)(2*ap)*512 + u], Wst[(size_t)(2*ap+1)*512 + u]);
}

// ---------------- M0[j][g] = sum_k wih0[j][k] * Wemb[k][g] ----------------
__global__ __launch_bounds__(128) void k_m0(const float* __restrict__ wih0,
                                            const float* __restrict__ Wemb,
                                            float* __restrict__ M0){
  int j = blockIdx.x, g = threadIdx.x;
  if (g < V1){
    float acc = 0.f;
    const float* wr = wih0 + (size_t)j*512;
    for (int k=0;k<512;k++) acc += wr[k] * Wemb[(size_t)k*V1 + g];
    M0[(size_t)j*112 + g] = acc;
  }
}

// ---------------- conv 3x3 SAME -> fpj bf16 (b,p,a); grid b32 x y8 x ah2 x xh4 ----------------
__global__ __launch_bounds__(256) void k_conv(const float* __restrict__ feat,
                                              const uintT* __restrict__ wtc,
                                              const float* __restrict__ bfv,
                                              ushortT* __restrict__ fpj){
  int bid = blockIdx.x;
  int b  = bid >> 6;
  int y  = (bid >> 3) & 7;
  int ah = (bid >> 2) & 1;
  int xh = bid & 3;
  int a  = ah*256 + threadIdx.x;
  int x0 = xh*8;
  float acc[8];
  float bias = bfv[a];
  #pragma unroll
  for (int x=0;x<8;x++) acc[x]=bias;
  for (int cp=0; cp<256; cp++){
    uintT wq[9];
    #pragma unroll
    for (int i=0;i<9;i++) wq[i] = wtc[((size_t)cp*9 + i)*512 + a];   // coalesced
    #pragma unroll
    for (int cc=0; cc<2; cc++){
      float w[9];
      #pragma unroll
      for (int i=0;i<9;i++) w[i] = cc ? bhi(wq[i]) : blo(wq[i]);
      #pragma unroll
      for (int ky=0; ky<3; ky++){
        int yy = y + ky - 1;
        if (yy < 0 || yy > 7) continue;       // uniform per block
        const float* fr = feat + (((size_t)b*512 + cp*2+cc)*8 + yy)*32 + x0;
        float in[10];
        in[0] = (x0 == 0)  ? 0.f : fr[-1];
        #pragma unroll
        for (int i=0;i<8;i++) in[i+1] = fr[i];
        in[9] = (x0 == 24) ? 0.f : fr[8];
        float w0=w[ky*3+0], w1=w[ky*3+1], w2=w[ky*3+2];
        #pragma unroll
        for (int x=0;x<8;x++)
          acc[x] += w0*in[x] + w1*in[x+1] + w2*in[x+2];
      }
    }
  }
  #pragma unroll
  for (int x=0;x<8;x++)
    fpj[((size_t)b*HWP + (size_t)(y*32 + x0 + x))*512 + a] = f2b(acc[x]);
}

// ---------------- stage half-K (256 k x 32 b) of [512][32] state into xs[k][36] ----------------
__device__ __forceinline__ void stage_half(float* __restrict__ xs,
                                           const float* __restrict__ srcT,
                                           int half, int tid){
  const float* s = srcT + half*8192;
  #pragma unroll
  for (int i=0;i<16;i++){
    int idx = tid + i*512;
    xs[(idx >> 5)*36 + (idx & 31)] = s[idx];
  }
}

// ---------------- bf16-weight GEMM quarter ----------------
__device__ __forceinline__ void gemm_half_b(float acc[4][4], const uintT* __restrict__ wb,
                                            const float* __restrict__ xs,
                                            int koff, int kq, int jq, int bq, int u0){
  const uintT* w0 = wb + ((size_t)(jq*512 + u0))*256 + ((koff + kq*16) >> 1);
  const float* xp = xs + (kq*16)*36 + bq*4;
  #pragma unroll
  for (int kk=0; kk<16; kk+=8){
    float xv[8][4];
    #pragma unroll
    for (int i=0;i<8;i++){
      float4 tv = *(const float4*)(xp + (kk+i)*36);
      xv[i][0]=tv.x; xv[i][1]=tv.y; xv[i][2]=tv.z; xv[i][3]=tv.w;
    }
    #pragma unroll
    for (int r=0;r<4;r++){
      uint4 wq = *(const uint4*)(w0 + (size_t)r*256 + (kk>>1));
      float wf[8] = {blo(wq.x),bhi(wq.x),blo(wq.y),bhi(wq.y),
                     blo(wq.z),bhi(wq.z),blo(wq.w),bhi(wq.w)};
      #pragma unroll
      for (int bb=0;bb<4;bb++){
        float s = 0.f;
        #pragma unroll
        for (int i=0;i<8;i++) s += wf[i]*xv[i][bb];
        acc[r][bb] += s;
      }
    }
  }
}

// ---------------- one pipeline stage: 128 A + 128 B + 32 att blocks ----------------
__global__ __launch_bounds__(512) void k_step(int L,
    const int* __restrict__ gt, const float* __restrict__ M0,
    const uintT* __restrict__ wgb,
    const float* __restrict__ bih0, const float* __restrict__ bhh0,
    const float* __restrict__ bih1, const float* __restrict__ bhh1,
    const ushortT* __restrict__ featb, const ushortT* __restrict__ fpj,
    const uintT* __restrict__ WstTb, const float* __restrict__ watt,
    const uintT* __restrict__ Woutb, const float* __restrict__ bout,
    float* __restrict__ st, float* __restrict__ out)
{
  __shared__ __align__(16) float pool[POOLF];
  const int tid = threadIdx.x, bid = blockIdx.x;
  float* h0p = st;               // 2 parities x [512][32]
  float* h1p = st + 32768;       // 2 parities x [512][32]
  float* c0T = st + 65536;
  float* c1T = st + 81920;

  if (bid < 256){
    float* xs   = pool;
    float* part = pool;          // overlay after GEMM
    float* gsum = pool + XS_F;
    const int kq = tid >> 5, jq = (tid >> 3) & 3, bq = tid & 7;

    if (bid < 128){
      // ======= role A: gates0(L) + cell0(L); reads h0(L-1), writes h0(L) =======
      const int t = L;
      if (t > STEPS-1) return;
      const int u0 = bid*4;
      const float* h0r = h0p + ((t+1)&1)*16384;
      float*       h0w = h0p + (t&1)*16384;
      const uintT* whh0b = wgb;

      float acc[4][4] = {{0.f}};
      stage_half(xs, h0r, 0, tid); __syncthreads();
      gemm_half_b(acc, whh0b, xs, 0,   kq, jq, bq, u0); __syncthreads();
      stage_half(xs, h0r, 1, tid); __syncthreads();
      gemm_half_b(acc, whh0b, xs, 256, kq, jq, bq, u0); __syncthreads();
      #pragma unroll
      for (int r=0;r<4;r++)
        #pragma unroll
        for (int bb=0;bb<4;bb++)
          part[(kq*16 + jq*4 + r)*33 + bq*4 + bb] = acc[r][bb];
      __syncthreads();
      {
        int jj = tid >> 5, b = tid & 31;
        float s = 0.f;
        #pragma unroll
        for (int k2=0;k2<16;k2++) s += part[(k2*16 + jj)*33 + b];
        int m = jj >> 2, ul = jj & 3;
        int j = m*512 + u0 + ul;
        s += bih0[j] + bhh0[j];
        if (t > 0) s += M0[(size_t)j*112 + gt[b*STEPS + t - 1]];
        gsum[jj*33 + b] = s;
      }
      __syncthreads();
      if (tid < 128){
        int ul = tid >> 5, b = tid & 31;
        float gi = gsum[(0*4+ul)*33 + b], gf = gsum[(1*4+ul)*33 + b];
        float gg = gsum[(2*4+ul)*33 + b], go = gsum[(3*4+ul)*33 + b];
        int idx = (u0+ul)*32 + b;
        float cn = sigf(gf)*c0T[idx] + sigf(gi)*tanh_f(gg);
        c0T[idx] = cn;
        h0w[idx] = sigf(go)*tanh_f(cn);
      }
    } else {
      // ======= role B: gates1(s)+cell1(s), s=L-1; reads h0(s), h1(s-1); writes h1(s) =======
      const int s = L - 1;
      if (s < 0 || s > STEPS-1) return;
      const int u0 = (bid-128)*4;
      const float* h0c = h0p + (s&1)*16384;
      const float* h1r = h1p + ((s+1)&1)*16384;
      float*       h1w = h1p + (s&1)*16384;
      const uintT* wih1b = wgb + 524288;
      const uintT* whh1b = wgb + 1048576;

      float acc[4][4] = {{0.f}};
      stage_half(xs, h0c, 0, tid); __syncthreads();
      gemm_half_b(acc, wih1b, xs, 0,   kq, jq, bq, u0); __syncthreads();
      stage_half(xs, h0c, 1, tid); __syncthreads();
      gemm_half_b(acc, wih1b, xs, 256, kq, jq, bq, u0); __syncthreads();
      stage_half(xs, h1r, 0, tid); __syncthreads();
      gemm_half_b(acc, whh1b, xs, 0,   kq, jq, bq, u0); __syncthreads();
      stage_half(xs, h1r, 1, tid); __syncthreads();
      gemm_half_b(acc, whh1b, xs, 256, kq, jq, bq, u0); __syncthreads();
      #pragma unroll
      for (int r=0;r<4;r++)
        #pragma unroll
        for (int bb=0;bb<4;bb++)
          part[(kq*16 + jq*4 + r)*33 + bq*4 + bb] = acc[r][bb];
      __syncthreads();
      {
        int jj = tid >> 5, b = tid & 31;
        float s2 = 0.f;
        #pragma unroll
        for (int k2=0;k2<16;k2++) s2 += part[(k2*16 + jj)*33 + b];
        int m = jj >> 2, ul = jj & 3;
        int j = m*512 + u0 + ul;
        s2 += bih1[j] + bhh1[j];
        gsum[jj*33 + b] = s2;
      }
      __syncthreads();
      if (tid < 128){
        int ul = tid >> 5, b = tid & 31;
        float gi = gsum[(0*4+ul)*33 + b], gf = gsum[(1*4+ul)*33 + b];
        float gg = gsum[(2*4+ul)*33 + b], go = gsum[(3*4+ul)*33 + b];
        int idx = (u0+ul)*32 + b;
        float cn = sigf(gf)*c1T[idx] + sigf(gi)*tanh_f(gg);
        c1T[idx] = cn;
        h1w[idx] = sigf(go)*tanh_f(cn);
      }
    }
    return;
  }

  // ======= role C: attention(r), r=L-2; reads h1(r); self-computes sp =======
  const int r = L - 2;
  if (r < 0 || r > STEPS-1) return;
  const int b = bid - 256;
  float* h1s   = pool;
  float* spsl  = pool + 512;
  float* spA   = pool + 1024;
  float* spB   = pool + 1536;
  float* watts = pool + 2048;
  float* pals  = pool + 2560;
  float* attw  = pool + 3072;
  float* glim  = pool + 3328;
  float* red   = pool + 3840;

  const float* h1c = h1p + (r&1)*16384;
  h1s[tid]   = h1c[tid*32 + b];
  watts[tid] = watt[tid];
  __syncthreads();

  // sp[a] = sum_u WstT[u][a] * h1[u]; split u-range across tid>>8, coalesced loads
  {
    int ap = tid & 255, uh = tid >> 8;
    float s0 = 0.f, s1 = 0.f;
    const uintT* wp = WstTb + ((size_t)uh*256)*256 + ap;
    #pragma unroll 8
    for (int u=0; u<256; u++){
      uintT wv = wp[(size_t)u*256];
      float h = h1s[uh*256 + u];
      s0 += blo(wv)*h; s1 += bhi(wv)*h;
    }
    spA[tid] = s0; spB[tid] = s1;
  }
  __syncthreads();
  {
    int apx = tid >> 1, i = tid & 1;
    spsl[tid] = i ? (spB[apx] + spB[256+apx]) : (spA[apx] + spA[256+apx]);
  }
  __syncthreads();

  // attention logits over (p, a-half)
  {
    int p = tid & 255, ac = tid >> 8;
    const uint4* fr = (const uint4*)(fpj + ((size_t)b*HWP + p)*512 + ac*256);
    float al2 = 0.f;
    #pragma unroll 8
    for (int kb=0;kb<32;kb++){
      uint4 q = fr[kb];
      float v[8] = {blo(q.x),bhi(q.x),blo(q.y),bhi(q.y),blo(q.z),bhi(q.z),blo(q.w),bhi(q.w)};
      int a0 = ac*256 + kb*8;
      #pragma unroll
      for (int i=0;i<8;i++)
        al2 += watts[a0+i] * tanh_f(v[i] + spsl[a0+i]);
    }
    pals[tid] = al2;
  }
  __syncthreads();
  // softmax over 256 positions
  {
    float al2 = (tid < 256) ? (pals[tid] + pals[256+tid]) : -1e30f;
    float m = al2;
    #pragma unroll
    for (int off=32; off>0; off>>=1) m = fmaxf(m, __shfl_xor(m, off));
    if (tid < 256 && (tid & 63)==0) red[tid>>6] = m;
    __syncthreads();
    m = fmaxf(fmaxf(red[0],red[1]), fmaxf(red[2],red[3]));
    float e = (tid < 256) ? __expf(al2 - m) : 0.f;
    float s = e;
    #pragma unroll
    for (int off=32; off>0; off>>=1) s += __shfl_xor(s, off);
    __syncthreads();
    if (tid < 256 && (tid & 63)==0) red[tid>>6] = s;
    __syncthreads();
    if (tid < 256){
      float sa = red[0]+red[1]+red[2]+red[3];
      attw[tid] = e / sa;
    }
  }
  __syncthreads();
  // glimpse[c] = sum_p featb[b,c,p] * attw[p]
  {
    const uint4* fr = (const uint4*)(featb + ((size_t)b*512 + tid)*HWP);
    float acc = 0.f;
    #pragma unroll 8
    for (int kb=0;kb<32;kb++){
      uint4 q = fr[kb];
      const float* aw = attw + kb*8;
      acc += blo(q.x)*aw[0] + bhi(q.x)*aw[1] + blo(q.y)*aw[2] + bhi(q.y)*aw[3]
           + blo(q.z)*aw[4] + bhi(q.z)*aw[5] + blo(q.w)*aw[6] + bhi(q.w)*aw[7];
    }
    glim[tid] = acc;
  }
  __syncthreads();
  // logits = [h1, glimpse] @ Wout^T + b_out (bf16 weights)
  if (tid < V1){
    const uint4* wr = (const uint4*)(Woutb + (size_t)tid*512);
    float acc = bout[tid];
    #pragma unroll 8
    for (int kb=0;kb<64;kb++){
      uint4 q = wr[kb];
      const float* hx = h1s + kb*8;
      acc += blo(q.x)*hx[0] + bhi(q.x)*hx[1] + blo(q.y)*hx[2] + bhi(q.y)*hx[3]
           + blo(q.z)*hx[4] + bhi(q.z)*hx[5] + blo(q.w)*hx[6] + bhi(q.w)*hx[7];
    }
    #pragma unroll 8
    for (int kb=0;kb<64;kb++){
      uint4 q = wr[64+kb];
      const float* gx = glim + kb*8;
      acc += blo(q.x)*gx[0] + bhi(q.x)*gx[1] + blo(q.y)*gx[2] + bhi(q.y)*gx[3]
           + blo(q.z)*gx[4] + bhi(q.z)*gx[5] + blo(q.w)*gx[6] + bhi(q.w)*gx[7];
    }
    out[(size_t)b*STEPS*V1 + (size_t)r*V1 + tid] = acc;
  }
}

extern "C" void kernel_launch(void* const* d_in, const int* in_sizes, int n_in,
                              void* d_out, int out_size, void* d_ws, size_t ws_size,
                              hipStream_t stream)
{
  const float* features = (const float*)d_in[0];
  const int*   gt       = (const int*)d_in[2];
  const float* Wf    = (const float*)d_in[3];
  const float* bfv   = (const float*)d_in[4];
  const float* Wst   = (const float*)d_in[5];
  const float* watt  = (const float*)d_in[6];
  const float* Wemb  = (const float*)d_in[7];
  const float* wih0  = (const float*)d_in[8];
  const float* whh0  = (const float*)d_in[9];
  const float* bih0  = (const float*)d_in[10];
  const float* bhh0  = (const float*)d_in[11];
  const float* wih1  = (const float*)d_in[12];
  const float* whh1  = (const float*)d_in[13];
  const float* bih1  = (const float*)d_in[14];
  const float* bhh1  = (const float*)d_in[15];
  const float* Wout  = (const float*)d_in[16];
  const float* bout  = (const float*)d_in[17];
  float* out = (float*)d_out;

  // ---- workspace layout (bytes), total ~25.1 MB; wtc overlaid by featb ----
  char* wsb = (char*)d_ws;
  ushortT* fpj   = (ushortT*)(wsb + 0);          //  8,388,608 persist
  uintT*   wtc   = (uintT*)  (wsb + 8388608);    //  4,718,592 transient (conv only)
  ushortT* featb = (ushortT*)(wsb + 8388608);    //  8,388,608 persist (written after conv)
  float*   M0    = (float*)  (wsb + 16777216);   //    917,504
  uintT*   wgb   = (uintT*)  (wsb + 17694720);   //  6,291,456 (whh0|wih1|whh1 bf16)
  uintT*   Woutb = (uintT*)  (wsb + 23986176);   //    227,328 (pad to 229,376)
  uintT*   WstTb = (uintT*)  (wsb + 24215552);   //    524,288
  float*   st    = (float*)  (wsb + 24739840);   //    393,216 (h0 x2, h1 x2, c0, c1)

  k_init <<<384, 256, 0, stream>>>(st);
  k_wgate<<<6144, 256, 0, stream>>>(whh0, wih1, whh1, wgb);
  k_wstT <<<512, 256, 0, stream>>>(Wst, WstTb);
  k_woutb<<<222, 256, 0, stream>>>(Wout, Woutb);
  k_m0   <<<2048, 128, 0, stream>>>(wih0, Wemb, M0);
  k_tconv<<<4608, 256, 0, stream>>>(Wf, wtc);
  k_conv <<<2048, 256, 0, stream>>>(features, wtc, bfv, fpj);
  k_featb<<<8192, 256, 0, stream>>>(features, (uintT*)featb);   // overwrites wtc region

  for (int L = 0; L < STEPS + 2; L++){
    k_step<<<288, 512, 0, stream>>>(L, gt, M0, wgb, bih0, bhh0, bih1, bhh1,
                                    featb, fpj, WstTb, watt, Woutb, bout, st, out);
  }
  (void)in_sizes; (void)n_in; (void)out_size; (void)ws_size;
}